// Round 5
// baseline (171.977 us; speedup 1.0000x reference)
//
#include <hip/hip_runtime.h>

#define POOLK 7
#define NBINS 49            // POOLK*POOLK
#define ALPHA 32
#define C4N   8             // ALPHA/4
#define HH    128
#define WW    128
#define NUM_ROIS 4096
#define F4_PER_PIX (NBINS * C4N)   // 392 float4 per (y,x) pixel
#define NXCD 8
#define SLOTS_PER_XCD 784          // 6272 / 8
#define CHUNKS_PER_PLANE 128       // 32768 threads per plane / 256
#define THREADS_PER_PLANE 32768

// img:  (1, 128, 128, 1568) f32  -> feat (128,128,49,32)
// rois: (1, 4096, 4) f32         -> (xmin, ymin, xmax, ymax) == one float4
// out:  (1, 4096, 7, 7, 32) f32  -> flat: rg*32 + c, rg = roi*49 + g, g = p*7+q
//
// Plane-banded XCD mapping (R3) + next-plane L2 prefetch + register-resident
// 16-deep gather (launch_bounds 256,2 -> 128 VGPR budget).
__global__ __launch_bounds__(256, 2) void psroi_align_kernel(
    const float4* __restrict__ feat,
    const float4* __restrict__ rois4,
    float4* __restrict__ out4)
{
    const int bid   = blockIdx.x;
    const int xcd   = bid & (NXCD - 1);
    const int j     = bid >> 3;                 // per-XCD sequence 0..783
    const int s     = xcd * SLOTS_PER_XCD + j;  // contiguous slot band per XCD
    const int g     = s >> 7;                   // plane 0..48
    const int chunk = s & (CHUNKS_PER_PLANE - 1);
    const int tpl   = (chunk << 8) + threadIdx.x;   // thread-in-plane 0..32767
    const int c4    = tpl & (C4N - 1);
    const int roi   = tpl >> 3;

    const float4 r = rois4[roi];           // x=xmin y=ymin z=xmax w=ymax

    const float step_x = (r.z - r.x) * (1.0f / POOLK);
    const float step_y = (r.w - r.y) * (1.0f / POOLK);

    const int p = g / POOLK;               // x bin
    const int q = g % POOLK;               // y bin

    const float x1 = r.x + (float)p * step_x;
    const float y1 = r.y + (float)q * step_y;

    const float scale = (float)(HH - 1);   // 127
    float ys[2], xs[2];
    ys[0] = y1 * scale;
    ys[1] = (y1 + step_y) * scale;
    xs[0] = x1 * scale;
    xs[1] = (x1 + step_x) * scale;

    float wy[2], wx[2];
    bool  vy[2], vx[2];
    int   yrow[4], xcol[4];                // {lo(s0),hi(s0),lo(s1),hi(s1)}
    #pragma unroll
    for (int sa = 0; sa < 2; ++sa) {
        const float yg = ys[sa];
        vy[sa] = (yg >= 0.0f) && (yg <= (float)(HH - 1));
        const float y0f = floorf(yg);
        wy[sa] = yg - y0f;
        int y0 = min(max((int)y0f, 0), HH - 1);
        yrow[2 * sa]     = y0;
        yrow[2 * sa + 1] = min(y0 + 1, HH - 1);

        const float xg = xs[sa];
        vx[sa] = (xg >= 0.0f) && (xg <= (float)(WW - 1));
        const float x0f = floorf(xg);
        wx[sa] = xg - x0f;
        int x0 = min(max((int)x0f, 0), WW - 1);
        xcol[2 * sa]     = x0;
        xcol[2 * sa + 1] = min(x0 + 1, WW - 1);
    }

    const int gbase = g * C4N + c4;

    int rowoff[4], coloff[4];
    #pragma unroll
    for (int i = 0; i < 4; ++i) {
        rowoff[i] = yrow[i] * (WW * F4_PER_PIX) + gbase;
        coloff[i] = xcol[i] * F4_PER_PIX;
    }

    // All 16 gather loads issued before any consumption.
    float4 ld[16];
    #pragma unroll
    for (int rr = 0; rr < 4; ++rr) {
        #pragma unroll
        for (int cc = 0; cc < 4; ++cc) {
            ld[rr * 4 + cc] = feat[rowoff[rr] + coloff[cc]];
        }
    }

    // Fire-and-forget prefetch of the NEXT plane into this XCD's L2.
    // 32768 threads/plane x 4 float4 = 2.1 MB = exactly plane gp.
    int gp = g + 1;
    if (gp >= NBINS) gp = 0;
    float4 pf[4];
    #pragma unroll
    for (int i = 0; i < 4; ++i) {
        const int k = i * THREADS_PER_PLANE + tpl;          // 0..131071, lanes coalesced
        pf[i] = feat[(k >> 3) * F4_PER_PIX + gp * C4N + (k & 7)];
    }

    // Nothing below may be hoisted above the loads.
    __builtin_amdgcn_sched_barrier(0);

    float4 vmax;
    vmax.x = -INFINITY; vmax.y = -INFINITY; vmax.z = -INFINITY; vmax.w = -INFINITY;

    #pragma unroll
    for (int sy = 0; sy < 2; ++sy) {
        #pragma unroll
        for (int sx = 0; sx < 2; ++sx) {
            const float w11 = wy[sy] * wx[sx];
            const float w10 = wy[sy] - w11;            // wy*(1-wx)
            const float w01 = wx[sx] - w11;            // (1-wy)*wx
            const float w00 = 1.0f - wy[sy] - wx[sx] + w11;

            const float4 v00 = ld[(2 * sy)     * 4 + (2 * sx)];
            const float4 v01 = ld[(2 * sy)     * 4 + (2 * sx + 1)];
            const float4 v10 = ld[(2 * sy + 1) * 4 + (2 * sx)];
            const float4 v11 = ld[(2 * sy + 1) * 4 + (2 * sx + 1)];

            float4 v;
            v.x = v00.x * w00 + v01.x * w01 + v10.x * w10 + v11.x * w11;
            v.y = v00.y * w00 + v01.y * w01 + v10.y * w10 + v11.y * w11;
            v.z = v00.z * w00 + v01.z * w01 + v10.z * w10 + v11.z * w11;
            v.w = v00.w * w00 + v01.w * w01 + v10.w * w10 + v11.w * w11;

            if (!(vy[sy] && vx[sx])) { v.x = 0.0f; v.y = 0.0f; v.z = 0.0f; v.w = 0.0f; }

            vmax.x = fmaxf(vmax.x, v.x);
            vmax.y = fmaxf(vmax.y, v.y);
            vmax.z = fmaxf(vmax.z, v.z);
            vmax.w = fmaxf(vmax.w, v.w);
        }
    }

    // out float4 index: (roi*49 + g)*8 + c4 ; 8 lanes (same roi) write 128 B contig
    out4[(roi * NBINS + g) * C4N + c4] = vmax;

    // Keep the prefetch results live so the loads aren't DCE'd.
    #pragma unroll
    for (int i = 0; i < 4; ++i) {
        asm volatile("" :: "v"(pf[i].x), "v"(pf[i].y), "v"(pf[i].z), "v"(pf[i].w));
    }
}

extern "C" void kernel_launch(void* const* d_in, const int* in_sizes, int n_in,
                              void* d_out, int out_size, void* d_ws, size_t ws_size,
                              hipStream_t stream) {
    const float4* feat = (const float4*)d_in[0];
    const float4* rois = (const float4*)d_in[1];
    float4* out = (float4*)d_out;

    const int grid = NXCD * SLOTS_PER_XCD;   // 6272 blocks, 256 thr each
    psroi_align_kernel<<<grid, 256, 0, stream>>>(feat, rois, out);
}